// Round 6
// baseline (456.599 us; speedup 1.0000x reference)
//
#include <hip/hip_runtime.h>
#include <hip/hip_bf16.h>

#define NTOK 49
#define NPAD 64
#define CDIM 128
#define C3   384
#define NHEAD 4
#define HDIM 32
#define SCALE 0.17677669529663687f

#define QS 136   // qs/ks row stride (elems): 272 B rows, 16B-aligned, +4 banks/row
#define VS 72    // vT row stride: 144 B rows, 16B-aligned

typedef __attribute__((ext_vector_type(8))) __bf16 bf16x8;
typedef __attribute__((ext_vector_type(4))) __bf16 bf16x4;
typedef __attribute__((ext_vector_type(4))) float f32x4;

#define PIN(v) asm volatile("" : "+v"(v))   // block load-rematerialization / sinking

// ws layout (bytes):
//   qkvT  __bf16[384][128]  @ 0        (98304 B)  qkvT[n][k]=qkv_w[k][n]; q rows pre-scaled
//   projT __bf16[128][128]  @ 98304    (32768 B)
//   blutT float [4][64][64] @ 131072   (65536 B)  TRANSPOSED bias LUT [h][ktok][qtok];
//                                                 ktok>=49 -> -1e30 (key mask)

__global__ __launch_bounds__(256) void prep_kernel(
    const float* __restrict__ qkv_w, const float* __restrict__ proj_w,
    const float* __restrict__ bias_table,
    __bf16* __restrict__ qkvT, __bf16* __restrict__ projT, float* __restrict__ blutT)
{
  int o = blockIdx.x * 256 + threadIdx.x;
  if (o < CDIM * C3) {
    int n = o >> 7, k = o & 127;
    float v = qkv_w[k * C3 + n];
    if (n < CDIM) v *= SCALE;              // fold softmax scale into q weights
    qkvT[o] = (__bf16)v;
  } else if (o < CDIM * C3 + CDIM * CDIM) {
    int o2 = o - CDIM * C3;
    int n = o2 >> 7, k = o2 & 127;
    projT[o2] = (__bf16)proj_w[k * CDIM + n];
  } else if (o < CDIM * C3 + CDIM * CDIM + NHEAD * NPAD * NPAD) {
    int t3 = o - (CDIM * C3 + CDIM * CDIM);
    int h = t3 >> 12, k = (t3 >> 6) & 63, q = t3 & 63;   // [h][ktok][qtok]
    float v;
    if (k >= NTOK) v = -1e30f;             // key mask: exp -> 0
    else if (q >= NTOK) v = 0.0f;          // pad queries: finite, rows never stored
    else {
      int idx = (q / 7 - k / 7 + 6) * 13 + (q % 7 - k % 7 + 6);
      v = bias_table[idx * NHEAD + h];
    }
    blutT[t3] = v;
  }
}

// 512 threads = 8 waves. LDS 53248 B -> 3 blocks/CU; launch_bounds(512,6) caps VGPR<=85
// so occupancy is LDS-limited at 24 waves/CU (6/SIMD).
__global__ __launch_bounds__(512, 6) void attn_kernel(
    const float* __restrict__ x, const float* __restrict__ qkv_b,
    const float* __restrict__ proj_b,
    const __bf16* __restrict__ qkvT, const __bf16* __restrict__ projT,
    const float* __restrict__ blutT, float* __restrict__ out)
{
  __shared__ __align__(16) char smem[53248];
  __bf16* qs_ = (__bf16*)smem;              // 64*136 (17408 B); phase2 aliased as O
  __bf16* ks_ = qs_ + NPAD * QS;            // 64*136 (17408 B); phase2 aliased as P
  __bf16* vT_ = ks_ + NPAD * QS;            // 128*72 (18432 B)

  const int tid  = threadIdx.x;
  const int wave = tid >> 6;                // 0..7
  const int lane = tid & 63;
  const int l15  = lane & 15;
  const int lg   = lane >> 4;

  const int win = blockIdx.x;
  const int b  = win >> 6;
  const int wh = (win >> 3) & 7;
  const int ww = win & 7;
  const float* xbase = x + (((b * 56) + wh * 7) * 56 + ww * 7) * CDIM;

  // ---- weight B-fragments for qkv GEMM (48 channels per wave), pinned ----
  const int nb = wave * 48;
  bf16x8 bq[3][4];
  #pragma unroll
  for (int nt = 0; nt < 3; ++nt)
    #pragma unroll
    for (int kt = 0; kt < 4; ++kt) {
      bq[nt][kt] = *(const bf16x8*)(qkvT + (nb + nt * 16 + l15) * CDIM + kt * 32 + lg * 8);
      PIN(bq[nt][kt]);
    }
  float qb[3];
  #pragma unroll
  for (int nt = 0; nt < 3; ++nt) {
    qb[nt] = qkv_b[nb + nt * 16 + l15];
    if (nb + nt * 16 < CDIM) qb[nt] *= SCALE;
  }

  // ---- phase 1: qkv GEMM. A-frags direct from global (L1/L2-hot window).
  // Pad tokens (t>=49) duplicate token 48: q-pad rows unused, k-pad rows killed by
  // blutT -1e30, v-pad rows multiplied by P=0. No zeroing needed.
  #pragma unroll 1
  for (int mt = 0; mt < 4; ++mt) {
    const int t  = mt * 16 + l15;
    const int tc = t < NTOK ? t : NTOK - 1;
    const float* src = xbase + ((tc / 7) * 56 + (tc % 7)) * CDIM + lg * 8;
    bf16x8 a[4];
    #pragma unroll
    for (int kt = 0; kt < 4; ++kt) {
      f32x4 x0 = *(const f32x4*)(src + kt * 32);
      f32x4 x1 = *(const f32x4*)(src + kt * 32 + 4);
      bf16x8 av;
      av[0] = (__bf16)x0[0]; av[1] = (__bf16)x0[1]; av[2] = (__bf16)x0[2]; av[3] = (__bf16)x0[3];
      av[4] = (__bf16)x1[0]; av[5] = (__bf16)x1[1]; av[6] = (__bf16)x1[2]; av[7] = (__bf16)x1[3];
      a[kt] = av;
    }
    f32x4 acc[3];
    #pragma unroll
    for (int nt = 0; nt < 3; ++nt) { acc[nt][0]=0.f; acc[nt][1]=0.f; acc[nt][2]=0.f; acc[nt][3]=0.f; }
    #pragma unroll
    for (int nt = 0; nt < 3; ++nt)
      #pragma unroll
      for (int kt = 0; kt < 4; ++kt)
        acc[nt] = __builtin_amdgcn_mfma_f32_16x16x32_bf16(a[kt], bq[nt][kt], acc[nt], 0, 0, 0);

    const int r0 = mt * 16 + lg * 4;
    #pragma unroll
    for (int nt = 0; nt < 3; ++nt) {
      const int n = nb + nt * 16 + l15;     // 16-col tiles never straddle q/k/v bounds
      if (n < CDIM) {                        // q (pre-scaled)
        #pragma unroll
        for (int i = 0; i < 4; ++i)
          qs_[(r0 + i) * QS + n] = (__bf16)(acc[nt][i] + qb[nt]);
      } else if (n < 2 * CDIM) {
        #pragma unroll
        for (int i = 0; i < 4; ++i)
          ks_[(r0 + i) * QS + (n - CDIM)] = (__bf16)(acc[nt][i] + qb[nt]);
      } else {                               // v transposed: vT[ch][token], b64 write
        bf16x4 vv;
        #pragma unroll
        for (int i = 0; i < 4; ++i) vv[i] = (__bf16)(acc[nt][i] + qb[nt]);
        *(bf16x4*)(vT_ + (n - 2 * CDIM) * VS + r0) = vv;
      }
    }
  }
  __syncthreads();   // q/k/v ready

  // ---- phase 2: attention, S^T formulation. wave = (head = wave&3, mh = wave>>2) ----
  const int h  = wave & 3;
  const int hc = h * HDIM;
  const int mh = wave >> 2;
  const float* bTh = blutT + h * 4096;

  // hoist K A-frags and V B-frags into regs (ks region is reused for P after barrier)
  bf16x8 bk[4];
  #pragma unroll
  for (int nt = 0; nt < 4; ++nt) {
    bk[nt] = *(const bf16x8*)(ks_ + (nt * 16 + l15) * QS + hc + lg * 8);
    PIN(bk[nt]);
  }
  bf16x8 bv[2][2];                           // [n16][kt2]
  #pragma unroll
  for (int n16 = 0; n16 < 2; ++n16)
    #pragma unroll
    for (int kt2 = 0; kt2 < 2; ++kt2) {
      bv[n16][kt2] = *(const bf16x8*)(vT_ + (hc + n16 * 16 + l15) * VS + kt2 * 32 + lg * 8);
      PIN(bv[n16][kt2]);
    }
  __syncthreads();   // all waves have bk/bv -> ks region becomes per-wave P scratch

  __bf16* O_ = qs_;                          // O aliases qs (wave-local row/col tile)
  __bf16* Pw = ks_ + wave * 16 * QS;         // per-wave P [16 qtok][64 ktok], stride QS

  #pragma unroll
  for (int mi = 0; mi < 2; ++mi) {
    const int m0 = (mh * 2 + mi) * 16;

    float bias[4][4];                        // [nt][i], lane-coalesced from blutT
    #pragma unroll
    for (int nt = 0; nt < 4; ++nt)
      #pragma unroll
      for (int i = 0; i < 4; ++i)
        bias[nt][i] = bTh[(nt * 16 + lg * 4 + i) * 64 + m0 + l15];

    // S^T = K·q^T : swap operands; col = l15 = qtok, row = ktok
    bf16x8 qB = *(const bf16x8*)(qs_ + (m0 + l15) * QS + hc + lg * 8);
    f32x4 s[4];
    #pragma unroll
    for (int nt = 0; nt < 4; ++nt) {
      f32x4 z; z[0]=0.f; z[1]=0.f; z[2]=0.f; z[3]=0.f;
      s[nt] = __builtin_amdgcn_mfma_f32_16x16x32_bf16(bk[nt], qB, z, 0, 0, 0);
    }
    // softmax over ktok: all 16 scores for this lane's qtok are IN-LANE
    float e[4][4];
    #pragma unroll
    for (int nt = 0; nt < 4; ++nt)
      #pragma unroll
      for (int i = 0; i < 4; ++i)
        e[nt][i] = __expf(s[nt][i] + bias[nt][i]);   // no max-sub: |s|<~10 << 88

    // P store first: depends only on exp, not on the sum reduction
    #pragma unroll
    for (int nt = 0; nt < 4; ++nt) {
      bf16x4 p4;
      p4[0] = (__bf16)e[nt][0]; p4[1] = (__bf16)e[nt][1];
      p4[2] = (__bf16)e[nt][2]; p4[3] = (__bf16)e[nt][3];
      *(bf16x4*)(Pw + l15 * QS + nt * 16 + lg * 4) = p4;
    }

    // sum over ktok: 15 in-lane adds + 2 shuffles; inv lives in "lane = qtok" layout
    float sum = ((e[0][0]+e[0][1])+(e[0][2]+e[0][3])) + ((e[1][0]+e[1][1])+(e[1][2]+e[1][3]))
              + ((e[2][0]+e[2][1])+(e[2][2]+e[2][3])) + ((e[3][0]+e[3][1])+(e[3][2]+e[3][3]));
    sum += __shfl_xor(sum, 16);
    sum += __shfl_xor(sum, 32);
    const float inv = __builtin_amdgcn_rcpf(sum);

    // LAYOUT TRANSPOSE (the R5 bug): O comes out with row = qtok = m0+lg*4+i, but
    // inv is per lane = qtok = m0+l15. Broadcast from lane lg*4+i (which holds
    // qtok m0+lg*4+i, since lg*4+i < 16). Chain hides under the PV MFMAs below.
    float invT[4];
    #pragma unroll
    for (int i = 0; i < 4; ++i) invT[i] = __shfl(inv, lg * 4 + i);

    // PV: A = P rows (b128), B = bv regs
    f32x4 o0, o1;
    o0[0]=0.f;o0[1]=0.f;o0[2]=0.f;o0[3]=0.f; o1[0]=0.f;o1[1]=0.f;o1[2]=0.f;o1[3]=0.f;
    #pragma unroll
    for (int kt2 = 0; kt2 < 2; ++kt2) {
      bf16x8 ap = *(const bf16x8*)(Pw + l15 * QS + kt2 * 32 + lg * 8);
      o0 = __builtin_amdgcn_mfma_f32_16x16x32_bf16(ap, bv[0][kt2], o0, 0, 0, 0);
      o1 = __builtin_amdgcn_mfma_f32_16x16x32_bf16(ap, bv[1][kt2], o1, 0, 0, 0);
    }
    const int r0 = m0 + lg * 4;
    #pragma unroll
    for (int i = 0; i < 4; ++i) {
      O_[(r0 + i) * QS + hc +      l15] = (__bf16)(o0[i] * invT[i]);
      O_[(r0 + i) * QS + hc + 16 + l15] = (__bf16)(o1[i] * invT[i]);
    }
  }
  __syncthreads();   // proj reads O rows across waves

  // ---- phase 3: proj GEMM, wave owns 16 output cols ----
  const int nb2 = wave * 16;
  bf16x8 bp[4];
  #pragma unroll
  for (int kt = 0; kt < 4; ++kt) {
    bp[kt] = *(const bf16x8*)(projT + (nb2 + l15) * CDIM + kt * 32 + lg * 8);
    PIN(bp[kt]);
  }
  const float pb = proj_b[nb2 + l15];
  float* outw = out + (((b * 56) + wh * 7) * 56 + ww * 7) * CDIM;

  #pragma unroll
  for (int mt = 0; mt < 4; ++mt) {
    bf16x8 ao[4];
    #pragma unroll
    for (int kt = 0; kt < 4; ++kt)
      ao[kt] = *(const bf16x8*)(O_ + (mt * 16 + l15) * QS + kt * 32 + lg * 8);
    f32x4 c0;
    c0[0]=0.f;c0[1]=0.f;c0[2]=0.f;c0[3]=0.f;
    #pragma unroll
    for (int kt = 0; kt < 4; ++kt)
      c0 = __builtin_amdgcn_mfma_f32_16x16x32_bf16(ao[kt], bp[kt], c0, 0, 0, 0);
    #pragma unroll
    for (int i = 0; i < 4; ++i) {
      const int r = mt * 16 + lg * 4 + i;
      if (r < NTOK) {
        float* po = outw + ((r / 7) * 56 + (r % 7)) * CDIM + nb2;
        po[l15] = c0[i] + pb;
      }
    }
  }
}

extern "C" void kernel_launch(void* const* d_in, const int* in_sizes, int n_in,
                              void* d_out, int out_size, void* d_ws, size_t ws_size,
                              hipStream_t stream) {
  const float* x          = (const float*)d_in[0];
  const float* qkv_w      = (const float*)d_in[1];
  const float* qkv_b      = (const float*)d_in[2];
  const float* proj_w     = (const float*)d_in[3];
  const float* proj_b     = (const float*)d_in[4];
  const float* bias_table = (const float*)d_in[5];

  __bf16* qkvT  = (__bf16*)d_ws;
  __bf16* projT = qkvT + C3 * CDIM;
  float*  blutT = (float*)((char*)d_ws + 131072);
  float*  out   = (float*)d_out;

  hipLaunchKernelGGL(prep_kernel, dim3(320), dim3(256), 0, stream,
                     qkv_w, proj_w, bias_table, qkvT, projT, blutT);
  hipLaunchKernelGGL(attn_kernel, dim3(4096), dim3(512), 0, stream,
                     x, qkv_b, proj_b, qkvT, projT, blutT, out);
}